// Round 6
// baseline (119.181 us; speedup 1.0000x reference)
//
#include <hip/hip_runtime.h>

// Smoothness loss, 1x3x224x224 f32, scalar f32 out.
// 64x1-pixel tiles (896 blocks, 3 blocks/CU resident -> 24 waves/CU),
// 8 waves = 8 window-row groups, LDS halo tile zero-padded, literal spatial
// weights, explicit kx+1 prefetch, per-block atomicAdd.

#define WSR 10
#define KK  21
#define HH  224
#define WW  224
#define HWSZ (HH*WW)
#define SIG_COLOR 50.0f
#define LPW 0.8f
#define C1T 10.0f
#define C2T 5.0f
#define ALPHA_W 5.0f
#define EPSV 1e-6f
#define LOG2E 1.44269504088896f
#define NSC (-SIG_COLOR * LOG2E)     // exp(-sc*cd) = exp2(NSC*cd)
#define SSP ((1.0f/98.0f) * LOG2E)   // exp(-d^2/98) = exp2(-SSP*d^2)

#define TX 64
#define HALO_W (TX + 2*WSR)      // 84
#define HALO_H (1 + 2*WSR)       // 21
#define HSZ (HALO_W * HALO_H)    // 1764
#define NBX 4
#define NBLK (NBX * HH)          // 896
#define SCALEF (1.0f / ((float)HWSZ * 100.0f))

__device__ __forceinline__ float fexp2(float x) { return __builtin_amdgcn_exp2f(x); }
__device__ __forceinline__ float flog2(float x) { return __builtin_amdgcn_logf(x); }

// exp(-(k-10)^2/98) as compile-time literals
static constexpr float WXT[KK] = {
  0.3604486f, 0.4375650f, 0.5204496f, 0.6065307f, 0.6925675f,
  0.7748383f, 0.8493658f, 0.9122539f, 0.9600054f, 0.9898479f,
  1.0f,
  0.9898479f, 0.9600054f, 0.9122539f, 0.8493658f, 0.7748383f,
  0.6925675f, 0.6065307f, 0.5204496f, 0.4375650f, 0.3604486f };

__global__ __launch_bounds__(512, 6) void smooth_loss_fused(
    const float* __restrict__ orig, const float* __restrict__ smo,
    float* __restrict__ out)
{
    __shared__ float2 tA[HSZ];   // (o0, o1)
    __shared__ float2 tB[HSZ];   // (o2, s0)
    __shared__ float2 tC[HSZ];   // (s1, s2)
    __shared__ float racc0[512], racc1[512], racc2[512], racc3[512];

    const int tid = threadIdx.x;
    const int bid = blockIdx.x;
    const int bx  = bid & (NBX - 1);
    const int by  = bid >> 2;            // pixel row 0..223

    // ---- stage zero-padded halo tile (84 x 21) ----
    const int gx0 = bx * TX - WSR;
    const int gy0 = by - WSR;
    for (int i = tid; i < HSZ; i += 512) {
        int r = i / HALO_W;
        int c = i - r * HALO_W;
        int gy = gy0 + r, gx = gx0 + c;
        bool v = ((unsigned)gy < (unsigned)HH) & ((unsigned)gx < (unsigned)WW);
        int gi = gy * WW + gx;
        float o0=0.f,o1=0.f,o2=0.f,s0=0.f,s1=0.f,s2=0.f;
        if (v) {
            o0 = orig[gi]; o1 = orig[gi+HWSZ]; o2 = orig[gi+2*HWSZ];
            s0 = smo[gi];  s1 = smo[gi+HWSZ]; s2 = smo[gi+2*HWSZ];
        }
        tA[i] = make_float2(o0,o1);
        tB[i] = make_float2(o2,s0);
        tC[i] = make_float2(s1,s2);
    }
    __syncthreads();

    // ---- window scan: wave kg handles rows {kg, kg+8, kg+16} (<21) ----
    const int lane = tid & 63;
    const int kg   = tid >> 6;           // 0..7

    const int cpos = WSR * HALO_W + (lane + WSR);
    const float2 cA = tA[cpos], cB = tB[cpos], cC = tC[cpos];
    const float oc0=cA.x, oc1=cA.y, oc2=cB.x, sc0=cB.y, sc1=cC.x, sc2=cC.y;

    float er_o=0.f, er_s=0.f, sl=0.f, ss=0.f;

    const int nrows = (kg < 5) ? 3 : 2;
    int ky = kg;
    for (int i = 0; i < nrows; ++i, ky += 8) {
        const float dyf = (float)(ky - WSR);
        const float wy = fexp2(-SSP * dyf * dyf);
        const float2* __restrict__ rA = &tA[ky * HALO_W + lane];
        const float2* __restrict__ rB = &tB[ky * HALO_W + lane];
        const float2* __restrict__ rC = &tC[ky * HALO_W + lane];
        float srow = 0.f;
        float2 A = rA[0], B = rB[0], C = rC[0];
        #pragma unroll
        for (int kx = 0; kx < KK; ++kx) {
            float2 A1 = A, B1 = B, C1 = C;
            if (kx < KK-1) { A1 = rA[kx+1]; B1 = rB[kx+1]; C1 = rC[kx+1]; }
            float e0 = A.x - oc0, e1 = A.y - oc1, e2 = B.x - oc2;
            float a0 = (A.x > 0.f) ? fabsf(e0) : 0.f;
            float a1 = (A.y > 0.f) ? fabsf(e1) : 0.f;
            float a2 = (B.x > 0.f) ? fabsf(e2) : 0.f;
            er_o += (a0 + a1) + a2;
            float t0 = (B.y > 0.f) ? fabsf(B.y - sc0) : 0.f;
            float t1 = (C.x > 0.f) ? fabsf(C.x - sc1) : 0.f;
            float t2 = (C.y > 0.f) ? fabsf(C.y - sc2) : 0.f;
            er_s += (t0 + t1) + t2;
            float cd = fmaf(e0, e0, fmaf(e1, e1, e2*e2));
            float wr = fexp2(NSC * cd);
            float tt = fmaf(t0, t0, fmaf(t1, t1, t2*t2));
            srow = fmaf(WXT[kx], tt, srow);
            float p0 = fexp2(LPW * flog2(t0 + EPSV));
            float p1 = fexp2(LPW * flog2(t1 + EPSV));
            float p2 = fexp2(LPW * flog2(t2 + EPSV));
            ss = fmaf(wr, (p0 + p1) + p2, ss);
            A = A1; B = B1; C = C1;
        }
        sl = fmaf(wy, srow, sl);
    }

    racc0[tid]=er_o; racc1[tid]=er_s; racc2[tid]=sl; racc3[tid]=ss;
    __syncthreads();

    // ---- per-pixel combine across the 8 row-groups (wave 0), select, reduce ----
    if (tid < 64) {
        float eo=0.f, es=0.f, l=0.f, s=0.f;
        #pragma unroll
        for (int k = 0; k < 8; ++k) {
            int idx = tid + 64 * k;
            eo += racc0[idx]; es += racc1[idx];
            l  += racc2[idx]; s  += racc3[idx];
        }
        bool use_large = (eo < C1T) && ((es - eo) > C2T);
        float contrib = use_large ? (ALPHA_W * l) : s;
        int px = bx * TX + tid;
        if (px >= WW) contrib = 0.f;      // dead lanes of bx==3
        #pragma unroll
        for (int off = 32; off > 0; off >>= 1)
            contrib += __shfl_down(contrib, off, 64);
        if (tid == 0)
            atomicAdd(out, contrib * SCALEF);
    }
}

extern "C" void kernel_launch(void* const* d_in, const int* in_sizes, int n_in,
                              void* d_out, int out_size, void* d_ws, size_t ws_size,
                              hipStream_t stream) {
    const float* orig = (const float*)d_in[0];   // original_images
    const float* smo  = (const float*)d_in[1];   // smooth_images
    float* out = (float*)d_out;

    hipMemsetAsync(d_out, 0, sizeof(float), stream);
    smooth_loss_fused<<<NBLK, 512, 0, stream>>>(orig, smo, out);
}

// Round 7
// 97.961 us; speedup vs baseline: 1.2166x; 1.2166x over previous
//
#include <hip/hip_runtime.h>

// Smoothness loss, 1x3x224x224 f32, scalar f32 out.
// 32x2-pixel tiles, 784 blocks, 448 threads = 7 waves; wave wv owns window
// rows {wv, wv+7, wv+14} (perfect balance, 21 rows). Lane = pixel (32 cols x
// 2 rows). LDS halo tile (52x22) zero-padded, literal spatial weights,
// row-factored sl, per-block atomicAdd.

#define WSR 10
#define KK  21
#define HH  224
#define WW  224
#define HWSZ (HH*WW)
#define SIG_COLOR 50.0f
#define LPW 0.8f
#define C1T 10.0f
#define C2T 5.0f
#define ALPHA_W 5.0f
#define EPSV 1e-6f
#define LOG2E 1.44269504088896f
#define NSC (-SIG_COLOR * LOG2E)     // exp(-sc*cd) = exp2(NSC*cd)
#define SSP ((1.0f/98.0f) * LOG2E)   // exp(-d^2/98) = exp2(-SSP*d^2)

#define TX 32
#define TY 2
#define HALO_W (TX + 2*WSR)      // 52
#define HALO_H (TY + 2*WSR)      // 22
#define HSZ (HALO_W * HALO_H)    // 1144
#define NBX (WW / TX)            // 7
#define NBY (HH / TY)            // 112
#define NBLK (NBX * NBY)         // 784
#define NTHR 448
#define SCALEF (1.0f / ((float)HWSZ * 100.0f))

__device__ __forceinline__ float fexp2(float x) { return __builtin_amdgcn_exp2f(x); }
__device__ __forceinline__ float flog2(float x) { return __builtin_amdgcn_logf(x); }

// exp(-(k-10)^2/98) as compile-time literals
static constexpr float WXT[KK] = {
  0.3604486f, 0.4375650f, 0.5204496f, 0.6065307f, 0.6925675f,
  0.7748383f, 0.8493658f, 0.9122539f, 0.9600054f, 0.9898479f,
  1.0f,
  0.9898479f, 0.9600054f, 0.9122539f, 0.8493658f, 0.7748383f,
  0.6925675f, 0.6065307f, 0.5204496f, 0.4375650f, 0.3604486f };

__global__ __launch_bounds__(NTHR) void smooth_loss_fused(
    const float* __restrict__ orig, const float* __restrict__ smo,
    float* __restrict__ out)
{
    __shared__ float2 tA[HSZ];   // (o0, o1)
    __shared__ float2 tB[HSZ];   // (o2, s0)
    __shared__ float2 tC[HSZ];   // (s1, s2)
    __shared__ float racc0[NTHR], racc1[NTHR], racc2[NTHR], racc3[NTHR];

    const int tid = threadIdx.x;
    const int bid = blockIdx.x;
    const int bx  = bid % NBX;
    const int by  = bid / NBX;           // pixel-row-pair 0..111

    // ---- stage zero-padded halo tile (52 x 22) ----
    const int gx0 = bx * TX - WSR;
    const int gy0 = by * TY - WSR;
    for (int i = tid; i < HSZ; i += NTHR) {
        int r = i / HALO_W;
        int c = i - r * HALO_W;
        int gy = gy0 + r, gx = gx0 + c;
        bool v = ((unsigned)gy < (unsigned)HH) & ((unsigned)gx < (unsigned)WW);
        int gi = gy * WW + gx;
        float o0=0.f,o1=0.f,o2=0.f,s0=0.f,s1=0.f,s2=0.f;
        if (v) {
            o0 = orig[gi]; o1 = orig[gi+HWSZ]; o2 = orig[gi+2*HWSZ];
            s0 = smo[gi];  s1 = smo[gi+HWSZ]; s2 = smo[gi+2*HWSZ];
        }
        tA[i] = make_float2(o0,o1);
        tB[i] = make_float2(o2,s0);
        tC[i] = make_float2(s1,s2);
    }
    __syncthreads();

    // ---- window scan: wave wv handles rows {wv, wv+7, wv+14} ----
    const int lane = tid & 63;
    const int wv   = tid >> 6;           // 0..6
    const int pr   = lane >> 5;          // pixel row in tile (0..1)
    const int pc   = lane & 31;          // pixel col in tile

    const int cpos = (WSR + pr) * HALO_W + (WSR + pc);
    const float2 cA = tA[cpos], cB = tB[cpos], cC = tC[cpos];
    const float oc0=cA.x, oc1=cA.y, oc2=cB.x, sc0=cB.y, sc1=cC.x, sc2=cC.y;

    float er_o=0.f, er_s=0.f, sl=0.f, ss=0.f;

    #pragma unroll
    for (int r = 0; r < 3; ++r) {
        const int ky = wv + 7 * r;       // 0..20, each exactly once per block
        const float dyf = (float)(ky - WSR);
        const float wy = fexp2(-SSP * dyf * dyf);
        const float2* __restrict__ rA = &tA[(pr + ky) * HALO_W + pc];
        const float2* __restrict__ rB = &tB[(pr + ky) * HALO_W + pc];
        const float2* __restrict__ rC = &tC[(pr + ky) * HALO_W + pc];
        float srow = 0.f;
        #pragma unroll
        for (int kx = 0; kx < KK; ++kx) {
            float2 A = rA[kx];
            float2 B = rB[kx];
            float2 C = rC[kx];
            float e0 = A.x - oc0, e1 = A.y - oc1, e2 = B.x - oc2;
            float a0 = (A.x > 0.f) ? fabsf(e0) : 0.f;
            float a1 = (A.y > 0.f) ? fabsf(e1) : 0.f;
            float a2 = (B.x > 0.f) ? fabsf(e2) : 0.f;
            er_o += (a0 + a1) + a2;
            float t0 = (B.y > 0.f) ? fabsf(B.y - sc0) : 0.f;
            float t1 = (C.x > 0.f) ? fabsf(C.x - sc1) : 0.f;
            float t2 = (C.y > 0.f) ? fabsf(C.y - sc2) : 0.f;
            er_s += (t0 + t1) + t2;
            float cd = fmaf(e0, e0, fmaf(e1, e1, e2*e2));
            float wr = fexp2(NSC * cd);                 // exp(-sig_color*cd)
            float tt = fmaf(t0, t0, fmaf(t1, t1, t2*t2));
            srow = fmaf(WXT[kx], tt, srow);             // literal weight
            float p0 = fexp2(LPW * flog2(t0 + EPSV));   // (t+eps)^0.8
            float p1 = fexp2(LPW * flog2(t1 + EPSV));
            float p2 = fexp2(LPW * flog2(t2 + EPSV));
            ss = fmaf(wr, (p0 + p1) + p2, ss);
        }
        sl = fmaf(wy, srow, sl);
    }

    racc0[tid]=er_o; racc1[tid]=er_s; racc2[tid]=sl; racc3[tid]=ss;
    __syncthreads();

    // ---- per-pixel combine across the 7 waves, select, reduce, atomic ----
    if (tid < 64) {
        float eo=0.f, es=0.f, l=0.f, s=0.f;
        #pragma unroll
        for (int k = 0; k < 7; ++k) {
            int idx = tid + 64 * k;
            eo += racc0[idx]; es += racc1[idx];
            l  += racc2[idx]; s  += racc3[idx];
        }
        bool use_large = (eo < C1T) && ((es - eo) > C2T);
        float contrib = use_large ? (ALPHA_W * l) : s;
        #pragma unroll
        for (int off = 32; off > 0; off >>= 1)
            contrib += __shfl_down(contrib, off, 64);
        if (tid == 0)
            atomicAdd(out, contrib * SCALEF);
    }
}

extern "C" void kernel_launch(void* const* d_in, const int* in_sizes, int n_in,
                              void* d_out, int out_size, void* d_ws, size_t ws_size,
                              hipStream_t stream) {
    const float* orig = (const float*)d_in[0];   // original_images
    const float* smo  = (const float*)d_in[1];   // smooth_images
    float* out = (float*)d_out;

    hipMemsetAsync(d_out, 0, sizeof(float), stream);
    smooth_loss_fused<<<NBLK, NTHR, 0, stream>>>(orig, smo, out);
}